// Round 1
// baseline (286.068 us; speedup 1.0000x reference)
//
#include <hip/hip_runtime.h>
#include <hip/hip_bf16.h>
#include <stdint.h>

#define SEQ      4096
#define BATCH    2
#define NTOK     (BATCH*SEQ)        // 8192
#define DMODEL   768
#define DINNER   1536
#define NHEADS   24
#define HEADDIM  64
#define DSTATE   16
#define NPAD     3328               // GEMM1 padded N (13*256)
#define EPSV     1e-5f
#define CHUNK    64
#define NCHUNK   (SEQ/CHUNK)        // 64
#define SUB      32
#define NT       12                 // GEMM1 K-tiles (768/64)

typedef __bf16 bf16x8 __attribute__((ext_vector_type(8)));
typedef float  floatx4 __attribute__((ext_vector_type(4)));

__device__ __forceinline__ unsigned short f2bf(float f) {
    union { float f; uint32_t u; } v; v.f = f;
    uint32_t u = v.u;
    uint32_t r = (u + 0x7fffu + ((u >> 16) & 1u)) >> 16;
    return (unsigned short)r;
}

__device__ __forceinline__ float bf2f(unsigned short h) {
    union { uint32_t u; float f; } v; v.u = (uint32_t)h << 16;
    return v.f;
}

__device__ __forceinline__ float bfl(uint32_t u) {
    union { uint32_t u; float f; } v; v.u = u << 16; return v.f;
}
__device__ __forceinline__ float bfh(uint32_t u) {
    union { uint32_t u; float f; } v; v.u = u & 0xffff0000u; return v.f;
}
__device__ __forceinline__ uint32_t packbf(float lo, float hi) {
    return (uint32_t)f2bf(lo) | ((uint32_t)f2bf(hi) << 16);
}

__device__ __forceinline__ float siluf(float x) { return x / (1.f + __expf(-x)); }

__device__ __forceinline__ void async_cp16(const void* g, void* l) {
    __builtin_amdgcn_global_load_lds(
        (const __attribute__((address_space(1))) void*)g,
        (__attribute__((address_space(3))) void*)l,
        16, 0, 0);
}

// ---------------------------------------------------------------------------
// Weight conversion.
// ---------------------------------------------------------------------------
__global__ __launch_bounds__(256) void cvt_kernel(
    const float* __restrict__ Win, const float* __restrict__ Wout,
    unsigned short* __restrict__ win16, unsigned short* __restrict__ wout16)
{
    int idx = blockIdx.x * 256 + threadIdx.x;
    const int n1 = NPAD * DMODEL;
    if (idx < n1) {
        int r = idx / DMODEL;
        win16[idx] = (r < 3128) ? f2bf(Win[idx]) : (unsigned short)0;
    } else {
        int i2 = idx - n1;
        if (i2 < DMODEL * DINNER) wout16[i2] = f2bf(Wout[i2]);
    }
}

// ---------------------------------------------------------------------------
// LayerNorm.  One wave per token.
// ---------------------------------------------------------------------------
__global__ __launch_bounds__(256) void ln_kernel(
    const float* __restrict__ x, const float* __restrict__ lnw, const float* __restrict__ lnb,
    unsigned short* __restrict__ u16)
{
    int wave = threadIdx.x >> 6, lane = threadIdx.x & 63;
    int token = blockIdx.x * 4 + wave;
    const float* row = x + (size_t)token * DMODEL;
    float4 v[3];
    float s = 0.f, ss = 0.f;
#pragma unroll
    for (int j = 0; j < 3; ++j) {
        v[j] = *(const float4*)(row + lane*4 + j*256);
        s  += v[j].x + v[j].y + v[j].z + v[j].w;
        ss += v[j].x*v[j].x + v[j].y*v[j].y + v[j].z*v[j].z + v[j].w*v[j].w;
    }
#pragma unroll
    for (int o = 32; o > 0; o >>= 1) { s += __shfl_xor(s, o, 64); ss += __shfl_xor(ss, o, 64); }
    float mean = s * (1.f/768.f);
    float var  = ss * (1.f/768.f) - mean*mean;
    float rstd = rsqrtf(var + EPSV);
    unsigned short* brow = u16 + (size_t)token * DMODEL;
#pragma unroll
    for (int j = 0; j < 3; ++j) {
        int cidx = lane*4 + j*256;
        float4 w4 = *(const float4*)(lnw + cidx);
        float4 b4 = *(const float4*)(lnb + cidx);
        float a0 = (v[j].x - mean)*rstd*w4.x + b4.x;
        float a1 = (v[j].y - mean)*rstd*w4.y + b4.y;
        float a2 = (v[j].z - mean)*rstd*w4.z + b4.z;
        float a3 = (v[j].w - mean)*rstd*w4.w + b4.w;
        ushort4 p; p.x = f2bf(a0); p.y = f2bf(a1); p.z = f2bf(a2); p.w = f2bf(a3);
        *(ushort4*)(brow + cidx) = p;
    }
}

// ---------------------------------------------------------------------------
// dt: softplus(raw + bias), dA = exp(dt * -exp(A_log)).
// ---------------------------------------------------------------------------
__global__ __launch_bounds__(256) void dt_kernel(
    const float* __restrict__ raw24, const float* __restrict__ dt_bias,
    const float* __restrict__ A_log, float* __restrict__ dtT, float* __restrict__ dAT)
{
    int tid = blockIdx.x * 256 + threadIdx.x;   // 0 .. NHEADS*NTOK-1
    int h   = tid >> 13;                        // NTOK = 8192
    int tok = tid & (NTOK-1);
    float raw = raw24[(size_t)tok*NHEADS + h] + dt_bias[h];
    float dt = (raw > 20.f) ? raw : log1pf(__expf(raw));
    float A = -__expf(A_log[h]);
    dtT[tid] = dt;
    dAT[tid] = __expf(dt * A);
}

// ---------------------------------------------------------------------------
// GEMM1: C = u16 @ win16^T.  256x256 tile, BK=64, 8 waves (512 thr), 8-phase
// schedule (T3+T4+T5): per phase {ds_read subtile | stage half-tile | barrier
// | lgkmcnt(0) | setprio(1) 16xMFMA setprio(0) | barrier}, counted vmcnt(4)
// once per K-tile (never 0 mid-loop).  LDS 128 KiB double-buffered, proven
// 8-way chunk-XOR swizzle (src-side pre-swizzle, linear LDS dest).
// Per-group staging: B0(t+1)@ph0, B1(t+1)@ph1 -> buf^1 (B reads of buf end
// ph1 of the *previous* group); A0+A1(t+2)@ph3 -> buf (A reads end ph2).
// vmcnt(4) at group end completes exactly tile t+1, leaves A(t+2) in flight.
// XCD swizzle: 416 blocks = 52 per XCD; each XCD owns 4 M-tiles (1.57 MB
// L2-resident A slice) sweeping 13 N-tiles.
// Epilogue split store: z16 | x16 | bcr(32 f32 cols) | raw24(24 f32 cols).
// ---------------------------------------------------------------------------
__global__ __launch_bounds__(512, 2) void gemm1_kernel(
    const unsigned short* __restrict__ A, const unsigned short* __restrict__ Bt,
    unsigned short* __restrict__ z16, unsigned short* __restrict__ x16,
    float* __restrict__ bcr, float* __restrict__ raw24)
{
    __shared__ unsigned short As[2][256*64];    // 64 KB
    __shared__ unsigned short Bs[2][256*64];    // 64 KB
    const int tid  = threadIdx.x;
    const int lane = tid & 63;
    const int wid  = tid >> 6;       // 0..7
    const int wr   = wid >> 2;       // 0..1  (M half: 128 rows)
    const int wc   = wid & 3;        // 0..3  (N quarter: 64 cols)

    const int id  = blockIdx.x;
    const int xcd = id & 7;
    const int jj  = id >> 3;         // 0..51
    const int mt  = xcd * 4 + (jj & 3);   // 0..31
    const int nt  = jj >> 2;              // 0..12
    const int m0  = mt * 256;
    const int n0  = nt * 256;

    // staging: 512 threads cover 64 rows x 64 cols per issue; dest linear
    // (base + lane*16B within each wave), source pre-swizzled by chunk XOR.
    const int srow = tid >> 3;               // 0..63
    const int sch  = tid & 7;
    const int ssc  = (sch ^ (srow & 7)) * 8;

    const unsigned short* Ag = A  + (size_t)(m0 + srow) * 768 + ssc;
    const unsigned short* Bg = Bt + (size_t)(n0 + srow) * 768 + ssc;
    unsigned short* AsD = &As[0][0] + srow * 64 + sch * 8;
    unsigned short* BsD = &Bs[0][0] + srow * 64 + sch * 8;

    auto stageA = [&](int bb, int ko) {      // both halves (rows 0..255), 4 loads
        const unsigned short* g = Ag + ko;
        unsigned short* d = AsD + bb * 16384;
        async_cp16(g,            d);
        async_cp16(g +  64*768,  d +  64*64);
        async_cp16(g + 128*768,  d + 128*64);
        async_cp16(g + 192*768,  d + 192*64);
    };
    auto stageB = [&](int bb, int h, int ko) {   // one half (128 rows), 2 loads
        const unsigned short* g = Bg + ko + (size_t)h * 128 * 768;
        unsigned short* d = BsD + bb * 16384 + h * 128 * 64;
        async_cp16(g,           d);
        async_cp16(g + 64*768,  d + 64*64);
    };

    floatx4 acc[8][4];
#pragma unroll
    for (int i = 0; i < 8; ++i)
#pragma unroll
        for (int j = 0; j < 4; ++j) acc[i][j] = floatx4{0.f, 0.f, 0.f, 0.f};

    const int fr  = lane & 15;
    const int q8  = lane >> 4;
    const int key = fr & 7;
    const int ch0 = (q8 ^ key) * 8;          // k-chunk 0..3 (ks=0)
    const int ch1 = ((4 + q8) ^ key) * 8;    // k-chunk 4..7 (ks=1)

    // prologue: tile0 (A+B) -> buf0, A(1) -> buf1; wait tile0, keep A(1) in flight
    stageA(0, 0);
    stageB(0, 0, 0);
    stageB(0, 1, 0);
    stageA(1, 64);
    asm volatile("s_waitcnt vmcnt(4)" ::: "memory");
    __builtin_amdgcn_s_barrier();

    for (int t = 0; t < NT; ++t) {
        const int b = t & 1;
        const unsigned short* ap = &As[0][0] + b * 16384 + (wr * 128 + fr) * 64;
        const unsigned short* bp = &Bs[0][0] + b * 16384 + (wc * 64 + fr) * 64;
        bf16x8 af[4][2], bf[4][2];

        // -------- phase 0: read a_lo(i0..3) + b_lo(j0..1); stage B0(t+1)
#pragma unroll
        for (int i = 0; i < 4; ++i) {
            af[i][0] = *(const bf16x8*)(ap + i*1024 + ch0);
            af[i][1] = *(const bf16x8*)(ap + i*1024 + ch1);
        }
#pragma unroll
        for (int j = 0; j < 2; ++j) {
            bf[j][0] = *(const bf16x8*)(bp + j*1024 + ch0);
            bf[j][1] = *(const bf16x8*)(bp + j*1024 + ch1);
        }
        if (t + 1 < NT) stageB(b ^ 1, 0, (t + 1) * 64);
        __builtin_amdgcn_s_barrier();
        asm volatile("s_waitcnt lgkmcnt(0)");
        __builtin_amdgcn_sched_barrier(0);
        __builtin_amdgcn_s_setprio(1);
#pragma unroll
        for (int i = 0; i < 4; ++i)
#pragma unroll
            for (int j = 0; j < 2; ++j) {
                acc[i][j] = __builtin_amdgcn_mfma_f32_16x16x32_bf16(af[i][0], bf[j][0], acc[i][j], 0, 0, 0);
                acc[i][j] = __builtin_amdgcn_mfma_f32_16x16x32_bf16(af[i][1], bf[j][1], acc[i][j], 0, 0, 0);
            }
        __builtin_amdgcn_s_setprio(0);
        __builtin_amdgcn_s_barrier();

        // -------- phase 1: read b_hi(j2..3); stage B1(t+1); MFMA i0..3 x j2..3
#pragma unroll
        for (int j = 2; j < 4; ++j) {
            bf[j][0] = *(const bf16x8*)(bp + j*1024 + ch0);
            bf[j][1] = *(const bf16x8*)(bp + j*1024 + ch1);
        }
        if (t + 1 < NT) stageB(b ^ 1, 1, (t + 1) * 64);
        __builtin_amdgcn_s_barrier();
        asm volatile("s_waitcnt lgkmcnt(0)");
        __builtin_amdgcn_sched_barrier(0);
        __builtin_amdgcn_s_setprio(1);
#pragma unroll
        for (int i = 0; i < 4; ++i)
#pragma unroll
            for (int j = 2; j < 4; ++j) {
                acc[i][j] = __builtin_amdgcn_mfma_f32_16x16x32_bf16(af[i][0], bf[j][0], acc[i][j], 0, 0, 0);
                acc[i][j] = __builtin_amdgcn_mfma_f32_16x16x32_bf16(af[i][1], bf[j][1], acc[i][j], 0, 0, 0);
            }
        __builtin_amdgcn_s_setprio(0);
        __builtin_amdgcn_s_barrier();

        // -------- phase 2: read a_hi(i4..7, overwrite af); MFMA i4..7 x j0..1
#pragma unroll
        for (int i = 0; i < 4; ++i) {
            af[i][0] = *(const bf16x8*)(ap + (i + 4)*1024 + ch0);
            af[i][1] = *(const bf16x8*)(ap + (i + 4)*1024 + ch1);
        }
        __builtin_amdgcn_s_barrier();
        asm volatile("s_waitcnt lgkmcnt(0)");
        __builtin_amdgcn_sched_barrier(0);
        __builtin_amdgcn_s_setprio(1);
#pragma unroll
        for (int i = 0; i < 4; ++i)
#pragma unroll
            for (int j = 0; j < 2; ++j) {
                acc[i+4][j] = __builtin_amdgcn_mfma_f32_16x16x32_bf16(af[i][0], bf[j][0], acc[i+4][j], 0, 0, 0);
                acc[i+4][j] = __builtin_amdgcn_mfma_f32_16x16x32_bf16(af[i][1], bf[j][1], acc[i+4][j], 0, 0, 0);
            }
        __builtin_amdgcn_s_setprio(0);
        __builtin_amdgcn_s_barrier();

        // -------- phase 3: stage A(t+2); MFMA i4..7 x j2..3; counted vmcnt
        if (t + 2 < NT) stageA(b, (t + 2) * 64);
        __builtin_amdgcn_s_barrier();
        asm volatile("s_waitcnt lgkmcnt(0)");
        __builtin_amdgcn_sched_barrier(0);
        __builtin_amdgcn_s_setprio(1);
#pragma unroll
        for (int i = 0; i < 4; ++i)
#pragma unroll
            for (int j = 2; j < 4; ++j) {
                acc[i+4][j] = __builtin_amdgcn_mfma_f32_16x16x32_bf16(af[i][0], bf[j][0], acc[i+4][j], 0, 0, 0);
                acc[i+4][j] = __builtin_amdgcn_mfma_f32_16x16x32_bf16(af[i][1], bf[j][1], acc[i+4][j], 0, 0, 0);
            }
        __builtin_amdgcn_s_setprio(0);
        if (t + 2 < NT) { asm volatile("s_waitcnt vmcnt(4)" ::: "memory"); }
        else            { asm volatile("s_waitcnt vmcnt(0)" ::: "memory"); }
        __builtin_amdgcn_s_barrier();
    }

    const int colx = lane & 15;
    const int rq   = (lane >> 4) * 4;
    const int gmb  = m0 + wr * 128;
    const int gnb  = n0 + wc * 64;
    if (nt < 6) {                           // tiles 0..5 -> z
#pragma unroll
        for (int i = 0; i < 8; ++i)
#pragma unroll
            for (int j = 0; j < 4; ++j)
#pragma unroll
                for (int r = 0; r < 4; ++r) {
                    int gm = gmb + i*16 + rq + r;
                    int gn = gnb + j*16 + colx;
                    z16[(size_t)gm * DINNER + gn] = f2bf(acc[i][j][r]);
                }
    } else if (nt < 12) {                   // tiles 6..11 -> x (bf16)
#pragma unroll
        for (int i = 0; i < 8; ++i)
#pragma unroll
            for (int j = 0; j < 4; ++j)
#pragma unroll
                for (int r = 0; r < 4; ++r) {
                    int gm = gmb + i*16 + rq + r;
                    int gn = gnb + j*16 + colx;
                    x16[(size_t)gm * DINNER + (gn - DINNER)] = f2bf(acc[i][j][r]);
                }
    } else {                                // tile 12: B/C -> bcr, dt -> raw24
#pragma unroll
        for (int i = 0; i < 8; ++i)
#pragma unroll
            for (int j = 0; j < 4; ++j)
#pragma unroll
                for (int r = 0; r < 4; ++r) {
                    int gm = gmb + i*16 + rq + r;
                    int gn = gnb + j*16 + colx;
                    if (gn < 3104)
                        bcr[(size_t)gm * 32 + (gn - 3072)] = acc[i][j][r];
                    else if (gn < 3128)
                        raw24[(size_t)gm * NHEADS + (gn - 3104)] = acc[i][j][r];
                }
    }
}

// ---------------------------------------------------------------------------
// GEMM2: out = g16 @ wout16^T + x.  Block 64x128, BK=64, XCD swizzle.
// ---------------------------------------------------------------------------
__global__ __launch_bounds__(256, 4) void gemm2_kernel(
    const unsigned short* __restrict__ A, const unsigned short* __restrict__ Bt,
    float* __restrict__ Cf, const float* __restrict__ resid)
{
    constexpr int K = DINNER;
    __shared__ unsigned short As[64*64];    //  8 KB
    __shared__ unsigned short Bs[128*64];   // 16 KB
    const int tid  = threadIdx.x;
    const int lane = tid & 63;
    const int wave = tid >> 6;
    const int id   = blockIdx.x;
    const int xcd  = id & 7;
    const int j6   = id >> 3;               // 0..95
    const int m0 = (xcd*16 + j6/6) * 64;
    const int n0 = (j6 % 6) * 128;
    const int wm = (wave & 1) * 32;
    const int wn = (wave >> 1) * 64;

    floatx4 acc[2][4];
#pragma unroll
    for (int i = 0; i < 2; ++i)
#pragma unroll
        for (int j = 0; j < 4; ++j) acc[i][j] = floatx4{0.f, 0.f, 0.f, 0.f};

    const int srow8  = lane >> 3;
    const int schunk = lane & 7;
    const int sscol  = (schunk ^ srow8) * 8;

    for (int k0 = 0; k0 < K; k0 += 64) {
        __syncthreads();
#pragma unroll
        for (int o = 0; o < 2; ++o) {
            int row = wave*16 + o*8 + srow8;
            async_cp16(A + (size_t)(m0 + row) * K + k0 + sscol, As + row*64 + schunk*8);
        }
#pragma unroll
        for (int o = 0; o < 4; ++o) {
            int row = wave*32 + o*8 + srow8;
            async_cp16(Bt + (size_t)(n0 + row) * K + k0 + sscol, Bs + row*64 + schunk*8);
        }
        __syncthreads();
        const int fr  = lane & 15;
        const int q8  = lane >> 4;
        const int key = fr & 7;
#pragma unroll
        for (int ks = 0; ks < 2; ++ks) {
            const int ch = ((ks*4 + q8) ^ key) * 8;
            bf16x8 a[2], b[4];
#pragma unroll
            for (int i = 0; i < 2; ++i)
                a[i] = *(const bf16x8*)(As + (wm + i*16 + fr)*64 + ch);
#pragma unroll
            for (int j = 0; j < 4; ++j)
                b[j] = *(const bf16x8*)(Bs + (wn + j*16 + fr)*64 + ch);
#pragma unroll
            for (int i = 0; i < 2; ++i)
#pragma unroll
                for (int j = 0; j < 4; ++j)
                    acc[i][j] = __builtin_amdgcn_mfma_f32_16x16x32_bf16(a[i], b[j], acc[i][j], 0, 0, 0);
        }
    }

    const int col = lane & 15;
    const int rq  = (lane >> 4) * 4;
#pragma unroll
    for (int i = 0; i < 2; ++i)
#pragma unroll
        for (int j = 0; j < 4; ++j)
#pragma unroll
            for (int r = 0; r < 4; ++r) {
                int gm = m0 + wm + i*16 + rq + r;
                int gn = n0 + wn + j*16 + col;
                Cf[(size_t)gm * DMODEL + gn] = acc[i][j][r] + resid[(size_t)gm * DMODEL + gn];
            }
}

// ---------------------------------------------------------------------------
// Pass 1: local scan (h init 0) with fused conv+silu, 4 chunks per 256-thr
// block.  B/C broadcasts read as float4 (ds_read_b128).
// ---------------------------------------------------------------------------
__global__ __launch_bounds__(256) void scan_pass1(
    const unsigned short* __restrict__ x16, const float* __restrict__ bcr,
    const float* __restrict__ dAT, const float* __restrict__ dtT,
    const float* __restrict__ cw, const float* __restrict__ cb, const float* __restrict__ Dp,
    float* __restrict__ hloc, float* __restrict__ pprod, unsigned short* __restrict__ ylocal16)
{
    int wave = threadIdx.x >> 6, lane = threadIdx.x & 63;
    int blk = blockIdx.x * 4 + wave;
    int c = blk & (NCHUNK-1), bh = blk >> 6;
    int h = bh % NHEADS, b = bh / NHEADS;
    int row0 = b * SEQ + c * CHUNK;
    int l0 = c * CHUNK;
    int tb = h * NTOK + row0;
    __shared__ float bcraw[4][35][32];
    __shared__ float bcsc[4][32][32];     // conv'd: 0..15 = B, 16..31 = C
    __shared__ float av[4][32], dv[4][32];

    const int cx = h*64 + lane;
    float cwx0 = cw[cx*4+0], cwx1 = cw[cx*4+1], cwx2 = cw[cx*4+2], cwx3 = cw[cx*4+3];
    float cbx = cb[cx];
    const int nBC = lane & 31;
    float cwc0 = cw[(DINNER+nBC)*4+0], cwc1 = cw[(DINNER+nBC)*4+1];
    float cwc2 = cw[(DINNER+nBC)*4+2], cwc3 = cw[(DINNER+nBC)*4+3];
    float cbc = cb[DINNER+nBC];
    float Dh = Dp[h];

    float xm3 = (l0 >= 3) ? bf2f(x16[(size_t)(row0-3)*DINNER + cx]) : 0.f;
    float xm2 = (l0 >= 2) ? bf2f(x16[(size_t)(row0-2)*DINNER + cx]) : 0.f;
    float xm1 = (l0 >= 1) ? bf2f(x16[(size_t)(row0-1)*DINNER + cx]) : 0.f;

    float hst[16];
#pragma unroll
    for (int n = 0; n < 16; ++n) hst[n] = 0.f;
    float aprod = 1.f;

    for (int sc = 0; sc < CHUNK/SUB; ++sc) {
        int rb = row0 + sc * SUB;
        int lb = l0 + sc * SUB;
        __syncthreads();
#pragma unroll
        for (int it = 0; it < 5; ++it) {        // B+C rows rb-3..rb+31 (35x8 float4)
            int idx = it*64 + lane;
            if (idx < 280) {
                int s = idx >> 3, q = idx & 7;
                float4 val = {0.f,0.f,0.f,0.f};
                if (lb - 3 + s >= 0)
                    val = *(const float4*)(bcr + (size_t)(rb-3+s)*32 + q*4);
                *(float4*)&bcraw[wave][s][q*4] = val;
            }
        }
        if (lane < 32) av[wave][lane] = dAT[(size_t)tb + sc*SUB + lane];
        else           dv[wave][lane-32] = dtT[(size_t)tb + sc*SUB + lane - 32];
        float xr[SUB];
#pragma unroll
        for (int s = 0; s < SUB; ++s)
            xr[s] = bf2f(x16[(size_t)(rb+s)*DINNER + cx]);
        __syncthreads();
#pragma unroll
        for (int it = 0; it < 16; ++it) {       // conv B,C -> bcsc
            int s = it*2 + (lane >> 5);
            float v = cbc + bcraw[wave][s][nBC]*cwc0 + bcraw[wave][s+1][nBC]*cwc1
                          + bcraw[wave][s+2][nBC]*cwc2 + bcraw[wave][s+3][nBC]*cwc3;
            bcsc[wave][s][nBC] = siluf(v);
        }
        __syncthreads();
#pragma unroll 2
        for (int s = 0; s < SUB; ++s) {
            float a = av[wave][s];
            float xc = siluf(cbx + xm3*cwx0 + xm2*cwx1 + xm1*cwx2 + xr[s]*cwx3);
            xm3 = xm2; xm2 = xm1; xm1 = xr[s];
            float scale = dv[wave][s] * xc;
            float y = Dh * xc;
            const float4* bp4 = (const float4*)&bcsc[wave][s][0];
            float4 bv[8];
#pragma unroll
            for (int q = 0; q < 8; ++q) bv[q] = bp4[q];      // 8x ds_read_b128
            const float* bp = (const float*)bv;
#pragma unroll
            for (int n = 0; n < 16; ++n) hst[n] = a*hst[n] + scale*bp[n];
#pragma unroll
            for (int n = 0; n < 16; ++n) y += hst[n] * bp[16+n];
            aprod *= a;
            ylocal16[(size_t)(rb+s)*DINNER + cx] = f2bf(y);
        }
    }
    float* o = hloc + (size_t)blk * 1024 + lane * 16;
#pragma unroll
    for (int n = 0; n < 16; ++n) o[n] = hst[n];
    if (lane == 0) pprod[blk] = aprod;
}

// Pass 2: sequential recombine over NCHUNK chunks per (b,h).
__global__ __launch_bounds__(64) void scan_pass2(
    const float* __restrict__ hloc, const float* __restrict__ pprod, float* __restrict__ hstart)
{
    int bh = blockIdx.x, lane = threadIdx.x;
    float hst[16];
#pragma unroll
    for (int n = 0; n < 16; ++n) hst[n] = 0.f;
    for (int c = 0; c < NCHUNK; ++c) {
        int blk = bh * NCHUNK + c;
        float* o = hstart + (size_t)blk * 1024 + lane * 16;
#pragma unroll
        for (int n = 0; n < 16; ++n) o[n] = hst[n];
        float P = pprod[blk];
        const float* hl = hloc + (size_t)blk * 1024 + lane * 16;
#pragma unroll
        for (int n = 0; n < 16; ++n) hst[n] = P * hst[n] + hl[n];
    }
}

// ---------------------------------------------------------------------------
// Pass 3 (lite): y[t] += cumdecay[t] * (C[t] . h_start), in-place, 4 chunks
// per block.  C read as float4.
// ---------------------------------------------------------------------------
__global__ __launch_bounds__(256) void scan_pass3(
    const float* __restrict__ bcr, const float* __restrict__ dAT,
    const float* __restrict__ cw, const float* __restrict__ cb,
    const float* __restrict__ hstart, unsigned short* __restrict__ ylocal16)
{
    int wave = threadIdx.x >> 6, lane = threadIdx.x & 63;
    int blk = blockIdx.x * 4 + wave;
    int c = blk & (NCHUNK-1), bh = blk >> 6;
    int h = bh % NHEADS, b = bh / NHEADS;
    int row0 = b * SEQ + c * CHUNK;
    int l0 = c * CHUNK;
    int tb = h * NTOK + row0;
    __shared__ float craw[4][35][16];
    __shared__ float csc[4][32][16];
    __shared__ float av[4][32];

    const int cx = h*64 + lane;
    const int nC = lane & 15;
    float cwc0 = cw[(DINNER+16+nC)*4+0], cwc1 = cw[(DINNER+16+nC)*4+1];
    float cwc2 = cw[(DINNER+16+nC)*4+2], cwc3 = cw[(DINNER+16+nC)*4+3];
    float cbc = cb[DINNER+16+nC];

    float h0[16];
    const float* hs = hstart + (size_t)blk * 1024 + lane * 16;
#pragma unroll
    for (int n = 0; n < 16; ++n) h0[n] = hs[n];
    float cd = 1.f;

    for (int sc = 0; sc < CHUNK/SUB; ++sc) {
        int rb = row0 + sc * SUB;
        int lb = l0 + sc * SUB;
        __syncthreads();
#pragma unroll
        for (int it = 0; it < 3; ++it) {        // C rows rb-3..rb+31 (35x4 float4)
            int idx = it*64 + lane;
            if (idx < 140) {
                int s = idx >> 2, q = idx & 3;
                float4 val = {0.f,0.f,0.f,0.f};
                if (lb - 3 + s >= 0)
                    val = *(const float4*)(bcr + (size_t)(rb-3+s)*32 + 16 + q*4);
                *(float4*)&craw[wave][s][q*4] = val;
            }
        }
        if (lane < 32) av[wave][lane] = dAT[(size_t)tb + sc*SUB + lane];
        float yr[SUB];
#pragma unroll
        for (int s = 0; s < SUB; ++s)
            yr[s] = bf2f(ylocal16[(size_t)(rb+s)*DINNER + cx]);
        __syncthreads();
#pragma unroll
        for (int it = 0; it < 8; ++it) {        // conv C -> csc
            int s = it*4 + (lane >> 4);
            float v = cbc + craw[wave][s][nC]*cwc0 + craw[wave][s+1][nC]*cwc1
                          + craw[wave][s+2][nC]*cwc2 + craw[wave][s+3][nC]*cwc3;
            csc[wave][s][nC] = siluf(v);
        }
        __syncthreads();
#pragma unroll 2
        for (int s = 0; s < SUB; ++s) {
            cd *= av[wave][s];
            const float4* cp4 = (const float4*)&csc[wave][s][0];
            float4 cv[4];
#pragma unroll
            for (int q = 0; q < 4; ++q) cv[q] = cp4[q];      // 4x ds_read_b128
            const float* cp = (const float*)cv;
            float corr = 0.f;
#pragma unroll
            for (int n = 0; n < 16; ++n) corr += cp[n] * h0[n];
            ylocal16[(size_t)(rb+s)*DINNER + cx] = f2bf(yr[s] + cd * corr);
        }
    }
}

// ---------------------------------------------------------------------------
// Gating + RMSNorm -> bf16 (16 B loads/stores)
// ---------------------------------------------------------------------------
__global__ __launch_bounds__(256) void gate_kernel(
    const unsigned short* __restrict__ yv16, const unsigned short* __restrict__ z16,
    const float* __restrict__ gw, unsigned short* __restrict__ g16)
{
    int wave = threadIdx.x >> 6, lane = threadIdx.x & 63;
    int token = blockIdx.x * 4 + wave;
    const uint4* yrow = (const uint4*)(yv16 + (size_t)token * DINNER);
    const uint4* zrow = (const uint4*)(z16 + (size_t)token * DINNER);
    float g[3][8];
    float ss = 0.f;
#pragma unroll
    for (int j = 0; j < 3; ++j) {
        uint4 y8 = yrow[lane + j*64];
        uint4 z8 = zrow[lane + j*64];
        const uint32_t* yp = (const uint32_t*)&y8;
        const uint32_t* zp = (const uint32_t*)&z8;
#pragma unroll
        for (int q = 0; q < 4; ++q) {
            float a = bfl(yp[q]) * siluf(bfl(zp[q]));
            float bvl = bfh(yp[q]) * siluf(bfh(zp[q]));
            g[j][q*2]   = a;
            g[j][q*2+1] = bvl;
            ss += a*a + bvl*bvl;
        }
    }
#pragma unroll
    for (int o = 32; o > 0; o >>= 1) ss += __shfl_xor(ss, o, 64);
    float scale = rsqrtf(ss * (1.f/1536.f) + EPSV);
    uint4* orow = (uint4*)(g16 + (size_t)token * DINNER);
#pragma unroll
    for (int j = 0; j < 3; ++j) {
        int ebase = (lane + j*64) * 8;
        float4 w0 = *(const float4*)(gw + ebase);
        float4 w1 = *(const float4*)(gw + ebase + 4);
        uint4 p;
        p.x = packbf(g[j][0]*scale*w0.x, g[j][1]*scale*w0.y);
        p.y = packbf(g[j][2]*scale*w0.z, g[j][3]*scale*w0.w);
        p.z = packbf(g[j][4]*scale*w1.x, g[j][5]*scale*w1.y);
        p.w = packbf(g[j][6]*scale*w1.z, g[j][7]*scale*w1.w);
        orow[lane + j*64] = p;
    }
}

// ---------------------------------------------------------------------------
extern "C" void kernel_launch(void* const* d_in, const int* in_sizes, int n_in,
                              void* d_out, int out_size, void* d_ws, size_t ws_size,
                              hipStream_t stream)
{
    const float* x        = (const float*)d_in[0];
    const float* ln_w     = (const float*)d_in[1];
    const float* ln_b     = (const float*)d_in[2];
    const float* W_in     = (const float*)d_in[3];
    const float* conv_w   = (const float*)d_in[4];
    const float* conv_b   = (const float*)d_in[5];
    const float* dt_bias  = (const float*)d_in[6];
    const float* A_log    = (const float*)d_in[7];
    const float* Dp       = (const float*)d_in[8];
    const float* gate_w   = (const float*)d_in[9];
    const float* W_out    = (const float*)d_in[10];
    float* out = (float*)d_out;

    char* ws = (char*)d_ws;
    size_t off = 0;
    auto alloc = [&](size_t bytes) -> void* {
        void* p = ws + off;
        off += (bytes + 255) & ~(size_t)255;
        return p;
    };
    unsigned short* u16    = (unsigned short*)alloc((size_t)NTOK*DMODEL*2);            // 12.58 MB
    unsigned short* win16  = (unsigned short*)alloc((size_t)NPAD*DMODEL*2);            //  5.11 MB
    float*          dtT    = (float*)alloc((size_t)NTOK*NHEADS*4);                     //  0.79 MB
    float*          dAT    = (float*)alloc((size_t)NTOK*NHEADS*4);                     //  0.79 MB
    float*          raw24  = (float*)alloc((size_t)NTOK*NHEADS*4);                     //  0.79 MB
    unsigned short* x16    = (unsigned short*)alloc((size_t)NTOK*DINNER*2);            // 25.17 MB
    float*          bcr    = (float*)alloc((size_t)NTOK*32*4);                         //  1.05 MB
    unsigned short* wout16 = (unsigned short*)alloc((size_t)DMODEL*DINNER*2);          //  2.36 MB
    unsigned short* z16    = (unsigned short*)alloc((size_t)NTOK*DINNER*2);            // 25.17 MB
    unsigned short* y16    = (unsigned short*)alloc((size_t)NTOK*DINNER*2);            // 25.17 MB
    unsigned short* g16    = (unsigned short*)alloc((size_t)NTOK*DINNER*2);            // 25.17 MB
    float*          pprod  = (float*)alloc((size_t)BATCH*NHEADS*NCHUNK*4);             //  0.01 MB
    // aliases (lifetime-checked):
    float* hloc   = (float*)u16;    // 12.58 MB == u16 size; u16 dead after gemm1
    float* hstart = (float*)g16;    // 12.58 MB <= g16; g16 first written at gate (after pass3)
    // high-water ~124 MB

    cvt_kernel<<<(NPAD*DMODEL + DMODEL*DINNER)/256, 256, 0, stream>>>(W_in, W_out, win16, wout16);
    ln_kernel<<<NTOK/4, 256, 0, stream>>>(x, ln_w, ln_b, u16);
    gemm1_kernel<<<416, 512, 0, stream>>>(u16, win16, z16, x16, bcr, raw24);
    dt_kernel<<<NTOK*NHEADS/256, 256, 0, stream>>>(raw24, dt_bias, A_log, dtT, dAT);
    scan_pass1<<<BATCH*NHEADS*NCHUNK/4, 256, 0, stream>>>(x16, bcr, dAT, dtT, conv_w, conv_b, Dp, hloc, pprod, y16);
    scan_pass2<<<BATCH*NHEADS, 64, 0, stream>>>(hloc, pprod, hstart);
    scan_pass3<<<BATCH*NHEADS*NCHUNK/4, 256, 0, stream>>>(bcr, dAT, conv_w, conv_b, hstart, y16);
    gate_kernel<<<NTOK/4, 256, 0, stream>>>(y16, z16, gate_w, g16);
    gemm2_kernel<<<768, 256, 0, stream>>>(g16, wout16, out, x);
}

// Round 2
// 261.791 us; speedup vs baseline: 1.0927x; 1.0927x over previous
//
#include <hip/hip_runtime.h>
#include <hip/hip_bf16.h>
#include <stdint.h>

#define SEQ      4096
#define BATCH    2
#define NTOK     (BATCH*SEQ)        // 8192
#define DMODEL   768
#define DINNER   1536
#define NHEADS   24
#define HEADDIM  64
#define DSTATE   16
#define NPAD     3200               // GEMM1 padded N (25*128)
#define EPSV     1e-5f
#define CHUNK    64
#define NCHUNK   (SEQ/CHUNK)        // 64
#define SUB      32

typedef __bf16 bf16x8 __attribute__((ext_vector_type(8)));
typedef float  floatx4 __attribute__((ext_vector_type(4)));

__device__ __forceinline__ unsigned short f2bf(float f) {
    union { float f; uint32_t u; } v; v.f = f;
    uint32_t u = v.u;
    uint32_t r = (u + 0x7fffu + ((u >> 16) & 1u)) >> 16;
    return (unsigned short)r;
}

__device__ __forceinline__ float bf2f(unsigned short h) {
    union { uint32_t u; float f; } v; v.u = (uint32_t)h << 16;
    return v.f;
}

__device__ __forceinline__ float bfl(uint32_t u) {
    union { uint32_t u; float f; } v; v.u = u << 16; return v.f;
}
__device__ __forceinline__ float bfh(uint32_t u) {
    union { uint32_t u; float f; } v; v.u = u & 0xffff0000u; return v.f;
}
__device__ __forceinline__ uint32_t packbf(float lo, float hi) {
    return (uint32_t)f2bf(lo) | ((uint32_t)f2bf(hi) << 16);
}

__device__ __forceinline__ float siluf(float x) { return x / (1.f + __expf(-x)); }

__device__ __forceinline__ void async_cp16(const void* g, void* l) {
    __builtin_amdgcn_global_load_lds(
        (const __attribute__((address_space(1))) void*)g,
        (__attribute__((address_space(3))) void*)l,
        16, 0, 0);
}

// ---------------------------------------------------------------------------
// Weight conversion.
// ---------------------------------------------------------------------------
__global__ __launch_bounds__(256) void cvt_kernel(
    const float* __restrict__ Win, const float* __restrict__ Wout,
    unsigned short* __restrict__ win16, unsigned short* __restrict__ wout16)
{
    int idx = blockIdx.x * 256 + threadIdx.x;
    const int n1 = NPAD * DMODEL;
    if (idx < n1) {
        int r = idx / DMODEL;
        win16[idx] = (r < 3128) ? f2bf(Win[idx]) : (unsigned short)0;
    } else {
        int i2 = idx - n1;
        if (i2 < DMODEL * DINNER) wout16[i2] = f2bf(Wout[i2]);
    }
}

// ---------------------------------------------------------------------------
// LayerNorm.  One wave per token.
// ---------------------------------------------------------------------------
__global__ __launch_bounds__(256) void ln_kernel(
    const float* __restrict__ x, const float* __restrict__ lnw, const float* __restrict__ lnb,
    unsigned short* __restrict__ u16)
{
    int wave = threadIdx.x >> 6, lane = threadIdx.x & 63;
    int token = blockIdx.x * 4 + wave;
    const float* row = x + (size_t)token * DMODEL;
    float4 v[3];
    float s = 0.f, ss = 0.f;
#pragma unroll
    for (int j = 0; j < 3; ++j) {
        v[j] = *(const float4*)(row + lane*4 + j*256);
        s  += v[j].x + v[j].y + v[j].z + v[j].w;
        ss += v[j].x*v[j].x + v[j].y*v[j].y + v[j].z*v[j].z + v[j].w*v[j].w;
    }
#pragma unroll
    for (int o = 32; o > 0; o >>= 1) { s += __shfl_xor(s, o, 64); ss += __shfl_xor(ss, o, 64); }
    float mean = s * (1.f/768.f);
    float var  = ss * (1.f/768.f) - mean*mean;
    float rstd = rsqrtf(var + EPSV);
    unsigned short* brow = u16 + (size_t)token * DMODEL;
#pragma unroll
    for (int j = 0; j < 3; ++j) {
        int cidx = lane*4 + j*256;
        float4 w4 = *(const float4*)(lnw + cidx);
        float4 b4 = *(const float4*)(lnb + cidx);
        float a0 = (v[j].x - mean)*rstd*w4.x + b4.x;
        float a1 = (v[j].y - mean)*rstd*w4.y + b4.y;
        float a2 = (v[j].z - mean)*rstd*w4.z + b4.z;
        float a3 = (v[j].w - mean)*rstd*w4.w + b4.w;
        ushort4 p; p.x = f2bf(a0); p.y = f2bf(a1); p.z = f2bf(a2); p.w = f2bf(a3);
        *(ushort4*)(brow + cidx) = p;
    }
}

// ---------------------------------------------------------------------------
// dt: softplus(raw + bias), dA = exp(dt * -exp(A_log)).
// ---------------------------------------------------------------------------
__global__ __launch_bounds__(256) void dt_kernel(
    const float* __restrict__ raw24, const float* __restrict__ dt_bias,
    const float* __restrict__ A_log, float* __restrict__ dtT, float* __restrict__ dAT)
{
    int tid = blockIdx.x * 256 + threadIdx.x;   // 0 .. NHEADS*NTOK-1
    int h   = tid >> 13;                        // NTOK = 8192
    int tok = tid & (NTOK-1);
    float raw = raw24[(size_t)tok*NHEADS + h] + dt_bias[h];
    float dt = (raw > 20.f) ? raw : log1pf(__expf(raw));
    float A = -__expf(A_log[h]);
    dtT[tid] = dt;
    dAT[tid] = __expf(dt * A);
}

// ---------------------------------------------------------------------------
// GEMM1: C = u16 @ win16^T.  Block 128x128, BK=64 (12 iters), wave tile 64x64,
// __launch_bounds__(256,3) -> 3 blocks/CU (acc=64 AGPR).  XCD swizzle:
// each XCD owns 8 M-tiles (1.57 MB A-slice, L2-resident), sweeps 25 N-tiles.
// 8-way chunk XOR LDS swizzle (src-side) -> 0 bank conflicts.
// Split store: z16 | x16 | bcr(f32 32 cols) | raw24(f32 24 cols).
// [R1 note: 256x256 8-phase rewrite regressed (63.8us, MfmaUtil 24%) --
//  K=768 is only 12 K-iters and 416x 1-block/CU blocks quantize to 2 rounds;
//  3-blocks/CU inter-block overlap beats lockstep deep pipeline here.]
// ---------------------------------------------------------------------------
__global__ __launch_bounds__(256, 3) void gemm1_kernel(
    const unsigned short* __restrict__ A, const unsigned short* __restrict__ Bt,
    unsigned short* __restrict__ z16, unsigned short* __restrict__ x16,
    float* __restrict__ bcr, float* __restrict__ raw24)
{
    constexpr int K = DMODEL;
    __shared__ unsigned short As[128*64];   // 16 KB
    __shared__ unsigned short Bs[128*64];   // 16 KB
    const int tid  = threadIdx.x;
    const int lane = tid & 63;
    const int wave = tid >> 6;
    const int id   = blockIdx.x;
    const int xcd  = id & 7;
    const int j5   = id >> 3;               // 0..199
    const int m0 = (xcd*8 + (j5 & 7)) * 128;
    const int n0 = (j5 >> 3) * 128;
    const int wm = (wave & 1) * 64;
    const int wn = (wave >> 1) * 64;

    floatx4 acc[4][4];
#pragma unroll
    for (int i = 0; i < 4; ++i)
#pragma unroll
        for (int j = 0; j < 4; ++j) acc[i][j] = floatx4{0.f, 0.f, 0.f, 0.f};

    const int srow8  = lane >> 3;                 // 0..7
    const int schunk = lane & 7;
    const int sscol  = (schunk ^ srow8) * 8;

    for (int k0 = 0; k0 < K; k0 += 64) {
        __syncthreads();
#pragma unroll
        for (int o = 0; o < 4; ++o) {             // A: wave rows [wave*32, +32)
            int row = wave*32 + o*8 + srow8;
            async_cp16(A + (size_t)(m0 + row) * K + k0 + sscol, As + row*64 + schunk*8);
        }
#pragma unroll
        for (int o = 0; o < 4; ++o) {             // B: wave rows [wave*32, +32)
            int row = wave*32 + o*8 + srow8;
            async_cp16(Bt + (size_t)(n0 + row) * K + k0 + sscol, Bs + row*64 + schunk*8);
        }
        __syncthreads();
        const int fr  = lane & 15;
        const int q8  = lane >> 4;
        const int key = fr & 7;
#pragma unroll
        for (int ks = 0; ks < 2; ++ks) {
            const int ch = ((ks*4 + q8) ^ key) * 8;
            bf16x8 a[4], b[4];
#pragma unroll
            for (int i = 0; i < 4; ++i)
                a[i] = *(const bf16x8*)(As + (wm + i*16 + fr)*64 + ch);
#pragma unroll
            for (int j = 0; j < 4; ++j)
                b[j] = *(const bf16x8*)(Bs + (wn + j*16 + fr)*64 + ch);
#pragma unroll
            for (int i = 0; i < 4; ++i)
#pragma unroll
                for (int j = 0; j < 4; ++j)
                    acc[i][j] = __builtin_amdgcn_mfma_f32_16x16x32_bf16(a[i], b[j], acc[i][j], 0, 0, 0);
        }
    }

    const int col = lane & 15;
    const int rq  = (lane >> 4) * 4;
    if (n0 < DINNER) {                      // tiles 0..11 -> z
#pragma unroll
        for (int i = 0; i < 4; ++i)
#pragma unroll
            for (int j = 0; j < 4; ++j)
#pragma unroll
                for (int r = 0; r < 4; ++r) {
                    int gm = m0 + wm + i*16 + rq + r;
                    int gn = n0 + wn + j*16 + col;
                    z16[(size_t)gm * DINNER + gn] = f2bf(acc[i][j][r]);
                }
    } else if (n0 < 3072) {                 // tiles 12..23 -> x (bf16)
#pragma unroll
        for (int i = 0; i < 4; ++i)
#pragma unroll
            for (int j = 0; j < 4; ++j)
#pragma unroll
                for (int r = 0; r < 4; ++r) {
                    int gm = m0 + wm + i*16 + rq + r;
                    int gn = n0 + wn + j*16 + col;
                    x16[(size_t)gm * DINNER + (gn - DINNER)] = f2bf(acc[i][j][r]);
                }
    } else {                                // tile 24: B/C -> bcr, dt -> raw24
#pragma unroll
        for (int i = 0; i < 4; ++i)
#pragma unroll
            for (int j = 0; j < 4; ++j)
#pragma unroll
                for (int r = 0; r < 4; ++r) {
                    int gm = m0 + wm + i*16 + rq + r;
                    int gn = n0 + wn + j*16 + col;
                    if (gn < 3104)
                        bcr[(size_t)gm * 32 + (gn - 3072)] = acc[i][j][r];
                    else if (gn < 3128)
                        raw24[(size_t)gm * NHEADS + (gn - 3104)] = acc[i][j][r];
                }
    }
}

// ---------------------------------------------------------------------------
// GEMM2: out = g16 @ wout16^T + x.  Block 64x128, BK=64, XCD swizzle.
// ---------------------------------------------------------------------------
__global__ __launch_bounds__(256, 4) void gemm2_kernel(
    const unsigned short* __restrict__ A, const unsigned short* __restrict__ Bt,
    float* __restrict__ Cf, const float* __restrict__ resid)
{
    constexpr int K = DINNER;
    __shared__ unsigned short As[64*64];    //  8 KB
    __shared__ unsigned short Bs[128*64];   // 16 KB
    const int tid  = threadIdx.x;
    const int lane = tid & 63;
    const int wave = tid >> 6;
    const int id   = blockIdx.x;
    const int xcd  = id & 7;
    const int j6   = id >> 3;               // 0..95
    const int m0 = (xcd*16 + j6/6) * 64;
    const int n0 = (j6 % 6) * 128;
    const int wm = (wave & 1) * 32;
    const int wn = (wave >> 1) * 64;

    floatx4 acc[2][4];
#pragma unroll
    for (int i = 0; i < 2; ++i)
#pragma unroll
        for (int j = 0; j < 4; ++j) acc[i][j] = floatx4{0.f, 0.f, 0.f, 0.f};

    const int srow8  = lane >> 3;
    const int schunk = lane & 7;
    const int sscol  = (schunk ^ srow8) * 8;

    for (int k0 = 0; k0 < K; k0 += 64) {
        __syncthreads();
#pragma unroll
        for (int o = 0; o < 2; ++o) {
            int row = wave*16 + o*8 + srow8;
            async_cp16(A + (size_t)(m0 + row) * K + k0 + sscol, As + row*64 + schunk*8);
        }
#pragma unroll
        for (int o = 0; o < 4; ++o) {
            int row = wave*32 + o*8 + srow8;
            async_cp16(Bt + (size_t)(n0 + row) * K + k0 + sscol, Bs + row*64 + schunk*8);
        }
        __syncthreads();
        const int fr  = lane & 15;
        const int q8  = lane >> 4;
        const int key = fr & 7;
#pragma unroll
        for (int ks = 0; ks < 2; ++ks) {
            const int ch = ((ks*4 + q8) ^ key) * 8;
            bf16x8 a[2], b[4];
#pragma unroll
            for (int i = 0; i < 2; ++i)
                a[i] = *(const bf16x8*)(As + (wm + i*16 + fr)*64 + ch);
#pragma unroll
            for (int j = 0; j < 4; ++j)
                b[j] = *(const bf16x8*)(Bs + (wn + j*16 + fr)*64 + ch);
#pragma unroll
            for (int i = 0; i < 2; ++i)
#pragma unroll
                for (int j = 0; j < 4; ++j)
                    acc[i][j] = __builtin_amdgcn_mfma_f32_16x16x32_bf16(a[i], b[j], acc[i][j], 0, 0, 0);
        }
    }

    const int col = lane & 15;
    const int rq  = (lane >> 4) * 4;
#pragma unroll
    for (int i = 0; i < 2; ++i)
#pragma unroll
        for (int j = 0; j < 4; ++j)
#pragma unroll
            for (int r = 0; r < 4; ++r) {
                int gm = m0 + wm + i*16 + rq + r;
                int gn = n0 + wn + j*16 + col;
                Cf[(size_t)gm * DMODEL + gn] = acc[i][j][r] + resid[(size_t)gm * DMODEL + gn];
            }
}

// ---------------------------------------------------------------------------
// Pass 1: local scan (h init 0) with fused conv+silu, 4 chunks per 256-thr
// block.  B/C broadcasts read as float4 (ds_read_b128).
// ---------------------------------------------------------------------------
__global__ __launch_bounds__(256) void scan_pass1(
    const unsigned short* __restrict__ x16, const float* __restrict__ bcr,
    const float* __restrict__ dAT, const float* __restrict__ dtT,
    const float* __restrict__ cw, const float* __restrict__ cb, const float* __restrict__ Dp,
    float* __restrict__ hloc, float* __restrict__ pprod, unsigned short* __restrict__ ylocal16)
{
    int wave = threadIdx.x >> 6, lane = threadIdx.x & 63;
    int blk = blockIdx.x * 4 + wave;
    int c = blk & (NCHUNK-1), bh = blk >> 6;
    int h = bh % NHEADS, b = bh / NHEADS;
    int row0 = b * SEQ + c * CHUNK;
    int l0 = c * CHUNK;
    int tb = h * NTOK + row0;
    __shared__ float bcraw[4][35][32];
    __shared__ float bcsc[4][32][32];     // conv'd: 0..15 = B, 16..31 = C
    __shared__ float av[4][32], dv[4][32];

    const int cx = h*64 + lane;
    float cwx0 = cw[cx*4+0], cwx1 = cw[cx*4+1], cwx2 = cw[cx*4+2], cwx3 = cw[cx*4+3];
    float cbx = cb[cx];
    const int nBC = lane & 31;
    float cwc0 = cw[(DINNER+nBC)*4+0], cwc1 = cw[(DINNER+nBC)*4+1];
    float cwc2 = cw[(DINNER+nBC)*4+2], cwc3 = cw[(DINNER+nBC)*4+3];
    float cbc = cb[DINNER+nBC];
    float Dh = Dp[h];

    float xm3 = (l0 >= 3) ? bf2f(x16[(size_t)(row0-3)*DINNER + cx]) : 0.f;
    float xm2 = (l0 >= 2) ? bf2f(x16[(size_t)(row0-2)*DINNER + cx]) : 0.f;
    float xm1 = (l0 >= 1) ? bf2f(x16[(size_t)(row0-1)*DINNER + cx]) : 0.f;

    float hst[16];
#pragma unroll
    for (int n = 0; n < 16; ++n) hst[n] = 0.f;
    float aprod = 1.f;

    for (int sc = 0; sc < CHUNK/SUB; ++sc) {
        int rb = row0 + sc * SUB;
        int lb = l0 + sc * SUB;
        __syncthreads();
#pragma unroll
        for (int it = 0; it < 5; ++it) {        // B+C rows rb-3..rb+31 (35x8 float4)
            int idx = it*64 + lane;
            if (idx < 280) {
                int s = idx >> 3, q = idx & 7;
                float4 val = {0.f,0.f,0.f,0.f};
                if (lb - 3 + s >= 0)
                    val = *(const float4*)(bcr + (size_t)(rb-3+s)*32 + q*4);
                *(float4*)&bcraw[wave][s][q*4] = val;
            }
        }
        if (lane < 32) av[wave][lane] = dAT[(size_t)tb + sc*SUB + lane];
        else           dv[wave][lane-32] = dtT[(size_t)tb + sc*SUB + lane - 32];
        float xr[SUB];
#pragma unroll
        for (int s = 0; s < SUB; ++s)
            xr[s] = bf2f(x16[(size_t)(rb+s)*DINNER + cx]);
        __syncthreads();
#pragma unroll
        for (int it = 0; it < 16; ++it) {       // conv B,C -> bcsc
            int s = it*2 + (lane >> 5);
            float v = cbc + bcraw[wave][s][nBC]*cwc0 + bcraw[wave][s+1][nBC]*cwc1
                          + bcraw[wave][s+2][nBC]*cwc2 + bcraw[wave][s+3][nBC]*cwc3;
            bcsc[wave][s][nBC] = siluf(v);
        }
        __syncthreads();
#pragma unroll 2
        for (int s = 0; s < SUB; ++s) {
            float a = av[wave][s];
            float xc = siluf(cbx + xm3*cwx0 + xm2*cwx1 + xm1*cwx2 + xr[s]*cwx3);
            xm3 = xm2; xm2 = xm1; xm1 = xr[s];
            float scale = dv[wave][s] * xc;
            float y = Dh * xc;
            const float4* bp4 = (const float4*)&bcsc[wave][s][0];
            float4 bv[8];
#pragma unroll
            for (int q = 0; q < 8; ++q) bv[q] = bp4[q];      // 8x ds_read_b128
            const float* bp = (const float*)bv;
#pragma unroll
            for (int n = 0; n < 16; ++n) hst[n] = a*hst[n] + scale*bp[n];
#pragma unroll
            for (int n = 0; n < 16; ++n) y += hst[n] * bp[16+n];
            aprod *= a;
            ylocal16[(size_t)(rb+s)*DINNER + cx] = f2bf(y);
        }
    }
    float* o = hloc + (size_t)blk * 1024 + lane * 16;
#pragma unroll
    for (int n = 0; n < 16; ++n) o[n] = hst[n];
    if (lane == 0) pprod[blk] = aprod;
}

// ---------------------------------------------------------------------------
// Pass 2: chunk-state recombination.  OLD version: 48 blocks x 64 thr =
// 48 CUs doing a 64-step sequential global scan (25 MB through ~1.1 TB/s of
// per-CU BW => ~20 us).  NEW: 192 blocks x 256 thr; each block owns a
// (b,h, column-quarter): bulk-load all 64 chunk states into LDS (coalesced
// float4, fully parallel), 64-step scan runs in LDS (stride-1, conflict-free),
// hstart streamed out per step.
// ---------------------------------------------------------------------------
__global__ __launch_bounds__(256) void scan_pass2(
    const float* __restrict__ hloc, const float* __restrict__ pprod, float* __restrict__ hstart)
{
    __shared__ float sm[64*256];            // 64 KB: [chunk][elem-quarter]
    __shared__ float pp[64];
    const int tid = threadIdx.x;
    const int bh  = blockIdx.x >> 2;
    const int q   = blockIdx.x & 3;
    const float* src = hloc + (size_t)bh * 65536 + q * 256;
#pragma unroll
    for (int it = 0; it < 16; ++it) {
        int idx = it*256 + tid;             // 0..4095
        int c   = idx >> 6;                 // 0..63
        int e4  = (idx & 63) * 4;           // 0..252
        *(float4*)&sm[c*256 + e4] = *(const float4*)(src + (size_t)c*1024 + e4);
    }
    if (tid < 64) pp[tid] = pprod[bh*64 + tid];
    __syncthreads();
    float h = 0.f;
    float* dst = hstart + (size_t)bh * 65536 + q * 256 + tid;
#pragma unroll 8
    for (int c = 0; c < 64; ++c) {
        dst[(size_t)c * 1024] = h;
        h = pp[c] * h + sm[c*256 + tid];
    }
}

// ---------------------------------------------------------------------------
// Pass 3 (lite): y[t] += cumdecay[t] * (C[t] . h_start), in-place, 4 chunks
// per block.  C read as float4.
// ---------------------------------------------------------------------------
__global__ __launch_bounds__(256) void scan_pass3(
    const float* __restrict__ bcr, const float* __restrict__ dAT,
    const float* __restrict__ cw, const float* __restrict__ cb,
    const float* __restrict__ hstart, unsigned short* __restrict__ ylocal16)
{
    int wave = threadIdx.x >> 6, lane = threadIdx.x & 63;
    int blk = blockIdx.x * 4 + wave;
    int c = blk & (NCHUNK-1), bh = blk >> 6;
    int h = bh % NHEADS, b = bh / NHEADS;
    int row0 = b * SEQ + c * CHUNK;
    int l0 = c * CHUNK;
    int tb = h * NTOK + row0;
    __shared__ float craw[4][35][16];
    __shared__ float csc[4][32][16];
    __shared__ float av[4][32];

    const int cx = h*64 + lane;
    const int nC = lane & 15;
    float cwc0 = cw[(DINNER+16+nC)*4+0], cwc1 = cw[(DINNER+16+nC)*4+1];
    float cwc2 = cw[(DINNER+16+nC)*4+2], cwc3 = cw[(DINNER+16+nC)*4+3];
    float cbc = cb[DINNER+16+nC];

    float h0[16];
    const float* hs = hstart + (size_t)blk * 1024 + lane * 16;
#pragma unroll
    for (int n = 0; n < 16; ++n) h0[n] = hs[n];
    float cd = 1.f;

    for (int sc = 0; sc < CHUNK/SUB; ++sc) {
        int rb = row0 + sc * SUB;
        int lb = l0 + sc * SUB;
        __syncthreads();
#pragma unroll
        for (int it = 0; it < 3; ++it) {        // C rows rb-3..rb+31 (35x4 float4)
            int idx = it*64 + lane;
            if (idx < 140) {
                int s = idx >> 2, q = idx & 3;
                float4 val = {0.f,0.f,0.f,0.f};
                if (lb - 3 + s >= 0)
                    val = *(const float4*)(bcr + (size_t)(rb-3+s)*32 + 16 + q*4);
                *(float4*)&craw[wave][s][q*4] = val;
            }
        }
        if (lane < 32) av[wave][lane] = dAT[(size_t)tb + sc*SUB + lane];
        float yr[SUB];
#pragma unroll
        for (int s = 0; s < SUB; ++s)
            yr[s] = bf2f(ylocal16[(size_t)(rb+s)*DINNER + cx]);
        __syncthreads();
#pragma unroll
        for (int it = 0; it < 8; ++it) {        // conv C -> csc
            int s = it*4 + (lane >> 4);
            float v = cbc + craw[wave][s][nC]*cwc0 + craw[wave][s+1][nC]*cwc1
                          + craw[wave][s+2][nC]*cwc2 + craw[wave][s+3][nC]*cwc3;
            csc[wave][s][nC] = siluf(v);
        }
        __syncthreads();
#pragma unroll 2
        for (int s = 0; s < SUB; ++s) {
            cd *= av[wave][s];
            const float4* cp4 = (const float4*)&csc[wave][s][0];
            float4 cv[4];
#pragma unroll
            for (int q = 0; q < 4; ++q) cv[q] = cp4[q];      // 4x ds_read_b128
            const float* cp = (const float*)cv;
            float corr = 0.f;
#pragma unroll
            for (int n = 0; n < 16; ++n) corr += cp[n] * h0[n];
            ylocal16[(size_t)(rb+s)*DINNER + cx] = f2bf(yr[s] + cd * corr);
        }
    }
}

// ---------------------------------------------------------------------------
// Gating + RMSNorm -> bf16 (16 B loads/stores)
// ---------------------------------------------------------------------------
__global__ __launch_bounds__(256) void gate_kernel(
    const unsigned short* __restrict__ yv16, const unsigned short* __restrict__ z16,
    const float* __restrict__ gw, unsigned short* __restrict__ g16)
{
    int wave = threadIdx.x >> 6, lane = threadIdx.x & 63;
    int token = blockIdx.x * 4 + wave;
    const uint4* yrow = (const uint4*)(yv16 + (size_t)token * DINNER);
    const uint4* zrow = (const uint4*)(z16 + (size_t)token * DINNER);
    float g[3][8];
    float ss = 0.f;
#pragma unroll
    for (int j = 0; j < 3; ++j) {
        uint4 y8 = yrow[lane + j*64];
        uint4 z8 = zrow[lane + j*64];
        const uint32_t* yp = (const uint32_t*)&y8;
        const uint32_t* zp = (const uint32_t*)&z8;
#pragma unroll
        for (int q = 0; q < 4; ++q) {
            float a = bfl(yp[q]) * siluf(bfl(zp[q]));
            float bvl = bfh(yp[q]) * siluf(bfh(zp[q]));
            g[j][q*2]   = a;
            g[j][q*2+1] = bvl;
            ss += a*a + bvl*bvl;
        }
    }
#pragma unroll
    for (int o = 32; o > 0; o >>= 1) ss += __shfl_xor(ss, o, 64);
    float scale = rsqrtf(ss * (1.f/1536.f) + EPSV);
    uint4* orow = (uint4*)(g16 + (size_t)token * DINNER);
#pragma unroll
    for (int j = 0; j < 3; ++j) {
        int ebase = (lane + j*64) * 8;
        float4 w0 = *(const float4*)(gw + ebase);
        float4 w1 = *(const float4*)(gw + ebase + 4);
        uint4 p;
        p.x = packbf(g[j][0]*scale*w0.x, g[j][1]*scale*w0.y);
        p.y = packbf(g[j][2]*scale*w0.z, g[j][3]*scale*w0.w);
        p.z = packbf(g[j][4]*scale*w1.x, g[j][5]*scale*w1.y);
        p.w = packbf(g[j][6]*scale*w1.z, g[j][7]*scale*w1.w);
        orow[lane + j*64] = p;
    }
}

// ---------------------------------------------------------------------------
extern "C" void kernel_launch(void* const* d_in, const int* in_sizes, int n_in,
                              void* d_out, int out_size, void* d_ws, size_t ws_size,
                              hipStream_t stream)
{
    const float* x        = (const float*)d_in[0];
    const float* ln_w     = (const float*)d_in[1];
    const float* ln_b     = (const float*)d_in[2];
    const float* W_in     = (const float*)d_in[3];
    const float* conv_w   = (const float*)d_in[4];
    const float* conv_b   = (const float*)d_in[5];
    const float* dt_bias  = (const float*)d_in[6];
    const float* A_log    = (const float*)d_in[7];
    const float* Dp       = (const float*)d_in[8];
    const float* gate_w   = (const float*)d_in[9];
    const float* W_out    = (const float*)d_in[10];
    float* out = (float*)d_out;

    char* ws = (char*)d_ws;
    size_t off = 0;
    auto alloc = [&](size_t bytes) -> void* {
        void* p = ws + off;
        off += (bytes + 255) & ~(size_t)255;
        return p;
    };
    unsigned short* u16    = (unsigned short*)alloc((size_t)NTOK*DMODEL*2);            // 12.58 MB
    unsigned short* win16  = (unsigned short*)alloc((size_t)NPAD*DMODEL*2);            //  4.92 MB
    float*          dtT    = (float*)alloc((size_t)NTOK*NHEADS*4);                     //  0.79 MB
    float*          dAT    = (float*)alloc((size_t)NTOK*NHEADS*4);                     //  0.79 MB
    float*          raw24  = (float*)alloc((size_t)NTOK*NHEADS*4);                     //  0.79 MB
    unsigned short* x16    = (unsigned short*)alloc((size_t)NTOK*DINNER*2);            // 25.17 MB
    float*          bcr    = (float*)alloc((size_t)NTOK*32*4);                         //  1.05 MB
    unsigned short* wout16 = (unsigned short*)alloc((size_t)DMODEL*DINNER*2);          //  2.36 MB
    unsigned short* z16    = (unsigned short*)alloc((size_t)NTOK*DINNER*2);            // 25.17 MB
    unsigned short* y16    = (unsigned short*)alloc((size_t)NTOK*DINNER*2);            // 25.17 MB
    unsigned short* g16    = (unsigned short*)alloc((size_t)NTOK*DINNER*2);            // 25.17 MB
    float*          pprod  = (float*)alloc((size_t)BATCH*NHEADS*NCHUNK*4);             //  0.01 MB
    // aliases (lifetime-checked):
    float* hloc   = (float*)u16;    // 12.58 MB == u16 size; u16 dead after gemm1
    float* hstart = (float*)g16;    // 12.58 MB <= g16; g16 first written at gate (after pass3)
    // high-water ~124 MB

    cvt_kernel<<<(NPAD*DMODEL + DMODEL*DINNER)/256, 256, 0, stream>>>(W_in, W_out, win16, wout16);
    ln_kernel<<<NTOK/4, 256, 0, stream>>>(x, ln_w, ln_b, u16);
    gemm1_kernel<<<1600, 256, 0, stream>>>(u16, win16, z16, x16, bcr, raw24);
    dt_kernel<<<NTOK*NHEADS/256, 256, 0, stream>>>(raw24, dt_bias, A_log, dtT, dAT);
    scan_pass1<<<BATCH*NHEADS*NCHUNK/4, 256, 0, stream>>>(x16, bcr, dAT, dtT, conv_w, conv_b, Dp, hloc, pprod, y16);
    scan_pass2<<<BATCH*NHEADS*4, 256, 0, stream>>>(hloc, pprod, hstart);
    scan_pass3<<<BATCH*NHEADS*NCHUNK/4, 256, 0, stream>>>(bcr, dAT, conv_w, conv_b, hstart, y16);
    gate_kernel<<<NTOK/4, 256, 0, stream>>>(y16, z16, gate_w, g16);
    gemm2_kernel<<<768, 256, 0, stream>>>(g16, wout16, out, x);
}